// Round 1
// 397.819 us; speedup vs baseline: 1.1017x; 1.1017x over previous
//
#include <hip/hip_runtime.h>

typedef _Float16 f16;
typedef _Float16 f16x8 __attribute__((ext_vector_type(8)));
typedef float    f32x4 __attribute__((ext_vector_type(4)));
typedef unsigned int   u32;
typedef unsigned short u16;

#define NCH   512
#define ND    16
#define NH    64
#define NW    64
#define HT    16                 // output rows per block (one 16-row MFMA tile)
#define ROWS  22                 // staged rows = 16 + 3 halo each side
#define RST   88                 // f16 per LDS row (176 B: 16B-aligned, dword stride 44 -> 2-way max)
#define PLANE 4096
#define CHVOL 65536
#define NFRAG 49                 // 7 kh * 7 kd B-fragments per channel
#define FRAG_U4_PER_CH (NFRAG * 64)   // one uint4 (f16x8) per lane per fragment

__device__ __forceinline__ u16 f16bits(float v) {
    return __builtin_bit_cast(u16, (f16)v);
}

// ---------------------------------------------------------------------------
// Prologue: fold w7 + centered(w5) + centered(w3) + identity into one 7^3
// effective kernel, then pre-expand the per-lane Toeplitz MFMA B-fragments:
//   frag[ch][kh][kd][lane] = f16x8 with element j = weff[kh][kd][tap],
//   tap = quad*8 + j - n - 5  (n=lane&15, quad=lane>>4), 0 outside [0,7).
// Identical f16 values the main kernel previously built per-kh with ~200
// VALU insts; now it's one coalesced 16B load per (kh,kd).
// ---------------------------------------------------------------------------
__global__ void build_weights(const float* __restrict__ w7,
                              const float* __restrict__ b7,
                              const float* __restrict__ w5,
                              const float* __restrict__ b5,
                              const float* __restrict__ w3,
                              const float* __restrict__ b3,
                              uint4* __restrict__ wfrag,
                              float* __restrict__ beff)
{
    __shared__ float weff[7][7][7];     // [kh][kd][kw]
    const int ch = blockIdx.x;
    const int t  = threadIdx.x;         // 64 threads = 1 wave

    for (int i = t; i < 343; i += 64) {
        const int kd = i / 49;
        const int r  = i - kd * 49;
        const int kh = r / 7;
        const int kw = r - kh * 7;
        float v = w7[ch * 343 + i];     // w7 layout [ch][kd][kh][kw]
        if (kd >= 1 && kd <= 5 && kh >= 1 && kh <= 5 && kw >= 1 && kw <= 5)
            v += w5[ch * 125 + (kd - 1) * 25 + (kh - 1) * 5 + (kw - 1)];
        if (kd >= 2 && kd <= 4 && kh >= 2 && kh <= 4 && kw >= 2 && kw <= 4)
            v += w3[ch * 27 + (kd - 2) * 9 + (kh - 2) * 3 + (kw - 2)];
        if (kd == 3 && kh == 3 && kw == 3) v += 1.0f;   // identity/residual
        weff[kh][kd][kw] = v;
    }
    __syncthreads();

    const int n    = t & 15;
    const int quad = t >> 4;
    uint4* wp = wfrag + ch * FRAG_U4_PER_CH + t;
    for (int kh = 0; kh < 7; ++kh) {
        for (int kd = 0; kd < 7; ++kd) {
            u32 pk[4];
            #pragma unroll
            for (int p = 0; p < 4; ++p) {
                const int t0 = quad * 8 + 2 * p - n - 5;
                const u32 lo = ((unsigned)t0       < 7u) ? (u32)f16bits(weff[kh][kd][t0])     : 0u;
                const u32 hi = ((unsigned)(t0 + 1) < 7u) ? (u32)f16bits(weff[kh][kd][t0 + 1]) : 0u;
                pk[p] = lo | (hi << 16);
            }
            wp[(kh * 7 + kd) * 64] = make_uint4(pk[0], pk[1], pk[2], pk[3]);
        }
    }
    if (t == 0) beff[ch] = b7[ch] + b5[ch] + b3[ch];
}

// ---------------------------------------------------------------------------
// Per-wave compute: one w-tile x one dout-group (8 douts). di range is the
// group's dout range dilated by the kd halo (+-3), clamped to [0,15].
// B-fragments for kh+1 are prefetched (vector loads) during kh's MFMAs.
// ---------------------------------------------------------------------------
template<int DILO, int DIHI, int G8>
__device__ __forceinline__ void conv_group(const u16* slab,
                                           const uint4* __restrict__ wfc,
                                           const uint4* bw0,
                                           int n, int quad, int w0, float bv,
                                           float* __restrict__ ob, int h0)
{
    f32x4 acc[8];
    #pragma unroll
    for (int t = 0; t < 8; ++t) acc[t] = (f32x4){bv, bv, bv, bv};

    uint4 bw[7];
    #pragma unroll
    for (int kd = 0; kd < 7; ++kd) bw[kd] = bw0[kd];

    #pragma unroll 1
    for (int kh = 0; kh < 7; ++kh) {
        // prefetch next kh's 7 fragments (clamped dummy reload on last iter)
        uint4 bwn[7];
        const int khn = (kh < 6) ? kh + 1 : 6;
        #pragma unroll
        for (int kd = 0; kd < 7; ++kd) bwn[kd] = wfc[(khn * 7 + kd) * 64];

        const u16* arow = slab + (n + kh) * RST + w0 + quad * 8;
        #pragma unroll
        for (int di = DILO; di <= DIHI; ++di) {
            const f16x8 Af = *(const f16x8*)(arow + di * (ROWS * RST));
            #pragma unroll
            for (int kd = 0; kd < 7; ++kd) {
                const int dout = di - kd + 3 - G8;       // folds at compile time
                if (dout < 0 || dout > 7) continue;
                acc[dout] = __builtin_amdgcn_mfma_f32_16x16x32_f16(
                                Af, __builtin_bit_cast(f16x8, bw[kd]), acc[dout], 0, 0, 0);
            }
        }
        #pragma unroll
        for (int kd = 0; kd < 7; ++kd) bw[kd] = bwn[kd];
    }

    // epilogue: D row = quad*4+r (h), col = n (w); out[..][h*64+w][G8 + d]
    #pragma unroll
    for (int r = 0; r < 4; ++r) {
        const int h = h0 + quad * 4 + r;
        float* p = ob + (h * NW + w0 + n) * ND + G8;
        #pragma unroll
        for (int tg = 0; tg < 2; ++tg) {
            const float4 v = make_float4(acc[4 * tg + 0][r], acc[4 * tg + 1][r],
                                         acc[4 * tg + 2][r], acc[4 * tg + 3][r]);
            *(float4*)(p + 4 * tg) = v;
        }
    }
}

// ---------------------------------------------------------------------------
// Main: block = (ch, 16-row h tile), 512 threads = 8 waves sharing one slab:
// wave = (w-tile 0..3) x (dout-group 0..1). Same LDS as before -> still
// 2 blocks/CU, but 16 waves/CU (4/SIMD) instead of 8.
// ---------------------------------------------------------------------------
__global__ __launch_bounds__(512, 4)
void dwconv_mfma(const float* __restrict__ in,
                 const uint4* __restrict__ wfrag,
                 const float* __restrict__ beff,
                 float* __restrict__ out)
{
    __shared__ u16 slab[ND * ROWS * RST];   // 61,952 B

    // XCD swizzle: same-channel h-tiles land on one XCD, adjacent in time.
    const int b     = blockIdx.x;
    const int xcd   = b & 7;
    const int local = b >> 3;                 // 0..255
    const int ch    = xcd * 64 + (local >> 2);
    const int ht    = local & 3;
    const int h0    = ht * HT;
    const int tid   = threadIdx.x;
    const int lane  = tid & 63;

    // issue kh=0 fragment loads + bias before staging so latency hides there
    const uint4* __restrict__ wfc = wfrag + ch * FRAG_U4_PER_CH + lane;
    uint4 bw0[7];
    #pragma unroll
    for (int kd = 0; kd < 7; ++kd) bw0[kd] = wfc[kd * 64];
    const float bv = beff[ch];

    const float* __restrict__ inb = in + ch * CHVOL;

    // ---- stage: chunks of 4 f16 (aligned float4 global load, b64 LDS write)
    for (int idx = tid; idx < ND * ROWS * 20; idx += 512) {
        const int di = idx / (ROWS * 20);
        const int rm = idx - di * (ROWS * 20);
        const int r  = rm / 20;
        const int c  = rm - r * 20;
        const int ih = h0 - 3 + r;
        u32 p0 = 0u, p1 = 0u;
        if ((unsigned)ih < (unsigned)NH && c >= 2 && c <= 17) {
            const float4 v = *(const float4*)(inb + di * PLANE + ih * NW + (c * 4 - 8));
            p0 = (u32)f16bits(v.x) | ((u32)f16bits(v.y) << 16);
            p1 = (u32)f16bits(v.z) | ((u32)f16bits(v.w) << 16);
        }
        *(uint2*)(slab + (di * ROWS + r) * RST + c * 4) = make_uint2(p0, p1);
    }
    __syncthreads();

    const int wv    = tid >> 6;       // 0..7
    const int wtile = wv & 3;         // w-tile
    const int g     = wv >> 1 & 0;    // placeholder (see below)
    (void)g;
    const int grp   = wv >> 2;        // dout group: douts grp*8 .. grp*8+7
    const int w0    = wtile * 16;
    const int n     = lane & 15;      // B/D column (also A row m)
    const int quad  = lane >> 4;

    float* __restrict__ ob = out + ch * CHVOL;

    if (grp == 0)
        conv_group<0, 10, 0>(slab, wfc, bw0, n, quad, w0, bv, ob, h0);
    else
        conv_group<5, 15, 8>(slab, wfc, bw0, n, quad, w0, bv, ob, h0);
}

extern "C" void kernel_launch(void* const* d_in, const int* in_sizes, int n_in,
                              void* d_out, int out_size, void* d_ws, size_t ws_size,
                              hipStream_t stream)
{
    const float* x  = (const float*)d_in[0];
    const float* w7 = (const float*)d_in[1];
    const float* b7 = (const float*)d_in[2];
    const float* w5 = (const float*)d_in[3];
    const float* b5 = (const float*)d_in[4];
    const float* w3 = (const float*)d_in[5];
    const float* b3 = (const float*)d_in[6];
    float* outp = (float*)d_out;

    uint4* wfrag = (uint4*)d_ws;                                  // 25,690,112 B
    float* beff  = (float*)((char*)d_ws
                            + (size_t)NCH * FRAG_U4_PER_CH * sizeof(uint4));

    build_weights<<<NCH, 64, 0, stream>>>(w7, b7, w5, b5, w3, b3, wfrag, beff);
    dwconv_mfma<<<NCH * 4, 512, 0, stream>>>(x, wfrag, beff, outp);
}

// Round 6
// 335.068 us; speedup vs baseline: 1.3081x; 1.1873x over previous
//
#include <hip/hip_runtime.h>

typedef _Float16 f16;
typedef _Float16 f16x8 __attribute__((ext_vector_type(8)));
typedef float    f32x4 __attribute__((ext_vector_type(4)));
typedef unsigned int   u32;
typedef unsigned short u16;

#define NCH   512
#define ND    16
#define NH    64
#define NW    64
#define HT    16                 // output rows per block (one 16-row MFMA tile)
#define ROWS  22                 // staged rows = 16 + 3 halo each side
#define RST   72                 // f16 per LDS row (144 B: 16B-aligned, 2-way banks)
#define PLANE 4096
#define CHVOL 65536
#define NFRAG 49                 // 7 kh * 7 kd B-fragments per channel
#define FRAG_U4_PER_CH (NFRAG * 64)   // one uint4 (f16x8) per lane per fragment
#define SLAB_U16 (ND * ROWS * RST)    // 25,344 u16 = 50,688 B (+16 B pad below)

__device__ __forceinline__ u16 f16bits(float v) {
    return __builtin_bit_cast(u16, (f16)v);
}

// ---------------------------------------------------------------------------
// Prologue: fold w7 + centered(w5) + centered(w3) + identity into one 7^3
// effective kernel, then pre-expand the per-lane Toeplitz MFMA B-fragments:
//   frag[ch][kh][kd][lane] = f16x8 with element j = weff[kh][kd][tap],
//   tap = quad*8 + j - n - 5  (n=lane&15, quad=lane>>4), 0 outside [0,7).
// Main kernel loads these as one coalesced 16B vector load per (kh,kd).
// ---------------------------------------------------------------------------
__global__ void build_weights(const float* __restrict__ w7,
                              const float* __restrict__ b7,
                              const float* __restrict__ w5,
                              const float* __restrict__ b5,
                              const float* __restrict__ w3,
                              const float* __restrict__ b3,
                              uint4* __restrict__ wfrag,
                              float* __restrict__ beff)
{
    __shared__ float weff[7][7][7];     // [kh][kd][kw]
    const int ch = blockIdx.x;
    const int t  = threadIdx.x;         // 64 threads = 1 wave

    for (int i = t; i < 343; i += 64) {
        const int kd = i / 49;
        const int r  = i - kd * 49;
        const int kh = r / 7;
        const int kw = r - kh * 7;
        float v = w7[ch * 343 + i];     // w7 layout [ch][kd][kh][kw]
        if (kd >= 1 && kd <= 5 && kh >= 1 && kh <= 5 && kw >= 1 && kw <= 5)
            v += w5[ch * 125 + (kd - 1) * 25 + (kh - 1) * 5 + (kw - 1)];
        if (kd >= 2 && kd <= 4 && kh >= 2 && kh <= 4 && kw >= 2 && kw <= 4)
            v += w3[ch * 27 + (kd - 2) * 9 + (kh - 2) * 3 + (kw - 2)];
        if (kd == 3 && kh == 3 && kw == 3) v += 1.0f;   // identity/residual
        weff[kh][kd][kw] = v;
    }
    __syncthreads();

    const int n    = t & 15;
    const int quad = t >> 4;
    uint4* wp = wfrag + ch * FRAG_U4_PER_CH + t;
    for (int kh = 0; kh < 7; ++kh) {
        for (int kd = 0; kd < 7; ++kd) {
            u32 pk[4];
            #pragma unroll
            for (int p = 0; p < 4; ++p) {
                const int t0 = quad * 8 + 2 * p - n - 5;
                const u32 lo = ((unsigned)t0       < 7u) ? (u32)f16bits(weff[kh][kd][t0])     : 0u;
                const u32 hi = ((unsigned)(t0 + 1) < 7u) ? (u32)f16bits(weff[kh][kd][t0 + 1]) : 0u;
                pk[p] = lo | (hi << 16);
            }
            wp[(kh * 7 + kd) * 64] = make_uint4(pk[0], pk[1], pk[2], pk[3]);
        }
    }
    if (t == 0) beff[ch] = b7[ch] + b5[ch] + b3[ch];
}

// ---------------------------------------------------------------------------
// Main: block = (ch, 16-row h tile), 256 threads = 4 waves = 4 w-tiles.
// Each wave computes a 16x16 (h,w) tile for ALL 16 douts -> full 64B
// coalesced output lines per wave (no write amplification / RFO).
// LDS slab shrunk to 50.7 KB -> 3 blocks/CU (12 waves/CU) for 3-way
// stage/compute phase overlap. B-fragments preloaded from workspace with
// one-kh lookahead (round-1 win, keeps VALU off the critical path).
// Right-edge A-reads (quad 3) intentionally overrun the row into the next
// row's left-halo zeros (their A data is out-of-image -> zero is correct);
// the final row's overrun lands in the zeroed 16B pad.
// ---------------------------------------------------------------------------
__global__ __launch_bounds__(256, 3)
void dwconv_mfma(const float* __restrict__ in,
                 const uint4* __restrict__ wfrag,
                 const float* __restrict__ beff,
                 float* __restrict__ out)
{
    __shared__ u16 slab[SLAB_U16 + 8];   // 50,704 B

    // XCD swizzle: same-channel h-tiles land on one XCD, adjacent in time.
    const int b     = blockIdx.x;
    const int xcd   = b & 7;
    const int local = b >> 3;                 // 0..255
    const int ch    = xcd * 64 + (local >> 2);
    const int ht    = local & 3;
    const int h0    = ht * HT;
    const int tid   = threadIdx.x;
    const int lane  = tid & 63;

    // issue kh=0 fragment loads + bias before staging so latency hides there
    const uint4* __restrict__ wfc = wfrag + ch * FRAG_U4_PER_CH + lane;
    uint4 bw[7];
    #pragma unroll
    for (int kd = 0; kd < 7; ++kd) bw[kd] = wfc[kd * 64];
    const float bv = beff[ch];

    const float* __restrict__ inb = in + ch * CHVOL;

    // ---- stage: chunks of 4 f16 (aligned float4 global load, b64 LDS write)
    // LDS col j = iw + 8 (halo 8 left); chunk c covers iw = 4c-8, c in 0..17.
    // c<2 and out-of-range rows are all-zero.
    for (int idx = tid; idx < ND * ROWS * 18; idx += 256) {
        const int di = idx / (ROWS * 18);
        const int rm = idx - di * (ROWS * 18);
        const int r  = rm / 18;
        const int c  = rm - r * 18;
        const int ih = h0 - 3 + r;
        u32 p0 = 0u, p1 = 0u;
        if ((unsigned)ih < (unsigned)NH && c >= 2) {
            const float4 v = *(const float4*)(inb + di * PLANE + ih * NW + (c * 4 - 8));
            p0 = (u32)f16bits(v.x) | ((u32)f16bits(v.y) << 16);
            p1 = (u32)f16bits(v.z) | ((u32)f16bits(v.w) << 16);
        }
        *(uint2*)(slab + (di * ROWS + r) * RST + c * 4) = make_uint2(p0, p1);
    }
    if (tid < 8) slab[SLAB_U16 + tid] = (u16)0;   // zero the overrun pad
    __syncthreads();

    const int wv    = tid >> 6;       // 0..3 -> w-tile
    const int w0    = wv * 16;
    const int n     = lane & 15;      // B/D column (also A row m)
    const int quad  = lane >> 4;

    f32x4 acc[16];
    #pragma unroll
    for (int t = 0; t < 16; ++t) acc[t] = (f32x4){bv, bv, bv, bv};

    #pragma unroll 1
    for (int kh = 0; kh < 7; ++kh) {
        // prefetch next kh's 7 fragments (clamped dummy reload on last iter)
        uint4 bwn[7];
        const int khn = (kh < 6) ? kh + 1 : 6;
        #pragma unroll
        for (int kd = 0; kd < 7; ++kd) bwn[kd] = wfc[(khn * 7 + kd) * 64];

        const u16* arow = slab + (n + kh) * RST + w0 + quad * 8;
        #pragma unroll
        for (int di = 0; di < ND; ++di) {
            const f16x8 Af = *(const f16x8*)(arow + di * (ROWS * RST));
            #pragma unroll
            for (int kd = 0; kd < 7; ++kd) {
                const int dout = di - kd + 3;            // folds at compile time
                if (dout < 0 || dout > 15) continue;
                acc[dout] = __builtin_amdgcn_mfma_f32_16x16x32_f16(
                                Af, __builtin_bit_cast(f16x8, bw[kd]), acc[dout], 0, 0, 0);
            }
        }
        #pragma unroll
        for (int kd = 0; kd < 7; ++kd) bw[kd] = bwn[kd];
    }

    // ---- epilogue: D row = quad*4+r (h), col = n (w); out[..][h*64+w][d]
    // Full 64B per point from one wave (proven-good plain float4 stores).
    float* __restrict__ ob = out + ch * CHVOL;
    #pragma unroll
    for (int r = 0; r < 4; ++r) {
        const int h = h0 + quad * 4 + r;
        float* p = ob + (h * NW + w0 + n) * ND;
        #pragma unroll
        for (int tg = 0; tg < 4; ++tg) {
            const float4 v = make_float4(acc[4 * tg + 0][r], acc[4 * tg + 1][r],
                                         acc[4 * tg + 2][r], acc[4 * tg + 3][r]);
            *(float4*)(p + 4 * tg) = v;
        }
    }
}

extern "C" void kernel_launch(void* const* d_in, const int* in_sizes, int n_in,
                              void* d_out, int out_size, void* d_ws, size_t ws_size,
                              hipStream_t stream)
{
    const float* x  = (const float*)d_in[0];
    const float* w7 = (const float*)d_in[1];
    const float* b7 = (const float*)d_in[2];
    const float* w5 = (const float*)d_in[3];
    const float* b5 = (const float*)d_in[4];
    const float* w3 = (const float*)d_in[5];
    const float* b3 = (const float*)d_in[6];
    float* outp = (float*)d_out;

    uint4* wfrag = (uint4*)d_ws;                                  // 25,690,112 B
    float* beff  = (float*)((char*)d_ws
                            + (size_t)NCH * FRAG_U4_PER_CH * sizeof(uint4));

    build_weights<<<NCH, 64, 0, stream>>>(w7, b7, w5, b5, w3, b3, wfrag, beff);
    dwconv_mfma<<<NCH * 4, 256, 0, stream>>>(x, wfrag, beff, outp);
}

// Round 7
// 318.274 us; speedup vs baseline: 1.3771x; 1.0528x over previous
//
#include <hip/hip_runtime.h>

typedef _Float16 f16;
typedef _Float16 f16x8 __attribute__((ext_vector_type(8)));
typedef float    f32x4 __attribute__((ext_vector_type(4)));
typedef unsigned int   u32;
typedef unsigned short u16;

#define NCH   512
#define ND    16
#define NH    64
#define NW    64
#define ROWS  70                 // 64 h rows + 3 zero-halo each side
#define RST   72                 // f16 per LDS row (144 B: 16B-aligned, 2-way banks)
#define PLANE 4096
#define CHVOL 65536
#define NFRAG 49                 // 7 kh * 7 kd B-fragments per channel
#define FRAG_U4_PER_CH (NFRAG * 64)   // one uint4 (f16x8) per lane per fragment
#define SLAB_U16 (ND * ROWS * RST)    // 80,640 u16 = 161,280 B (+16 B pad below)

__device__ __forceinline__ u16 f16bits(float v) {
    return __builtin_bit_cast(u16, (f16)v);
}

// ---------------------------------------------------------------------------
// Prologue: fold w7 + centered(w5) + centered(w3) + identity into one 7^3
// effective kernel, then pre-expand the per-lane Toeplitz MFMA B-fragments:
//   frag[ch][kh][kd][lane] = f16x8 with element j = weff[kh][kd][tap],
//   tap = quad*8 + j - n - 5  (n=lane&15, quad=lane>>4), 0 outside [0,7).
// Main kernel loads these as one coalesced 16B vector load per (kh,kd).
// ---------------------------------------------------------------------------
__global__ void build_weights(const float* __restrict__ w7,
                              const float* __restrict__ b7,
                              const float* __restrict__ w5,
                              const float* __restrict__ b5,
                              const float* __restrict__ w3,
                              const float* __restrict__ b3,
                              uint4* __restrict__ wfrag,
                              float* __restrict__ beff)
{
    __shared__ float weff[7][7][7];     // [kh][kd][kw]
    const int ch = blockIdx.x;
    const int t  = threadIdx.x;         // 64 threads = 1 wave

    for (int i = t; i < 343; i += 64) {
        const int kd = i / 49;
        const int r  = i - kd * 49;
        const int kh = r / 7;
        const int kw = r - kh * 7;
        float v = w7[ch * 343 + i];     // w7 layout [ch][kd][kh][kw]
        if (kd >= 1 && kd <= 5 && kh >= 1 && kh <= 5 && kw >= 1 && kw <= 5)
            v += w5[ch * 125 + (kd - 1) * 25 + (kh - 1) * 5 + (kw - 1)];
        if (kd >= 2 && kd <= 4 && kh >= 2 && kh <= 4 && kw >= 2 && kw <= 4)
            v += w3[ch * 27 + (kd - 2) * 9 + (kh - 2) * 3 + (kw - 2)];
        if (kd == 3 && kh == 3 && kw == 3) v += 1.0f;   // identity/residual
        weff[kh][kd][kw] = v;
    }
    __syncthreads();

    const int n    = t & 15;
    const int quad = t >> 4;
    uint4* wp = wfrag + ch * FRAG_U4_PER_CH + t;
    for (int kh = 0; kh < 7; ++kh) {
        for (int kd = 0; kd < 7; ++kd) {
            u32 pk[4];
            #pragma unroll
            for (int p = 0; p < 4; ++p) {
                const int t0 = quad * 8 + 2 * p - n - 5;
                const u32 lo = ((unsigned)t0       < 7u) ? (u32)f16bits(weff[kh][kd][t0])     : 0u;
                const u32 hi = ((unsigned)(t0 + 1) < 7u) ? (u32)f16bits(weff[kh][kd][t0 + 1]) : 0u;
                pk[p] = lo | (hi << 16);
            }
            wp[(kh * 7 + kd) * 64] = make_uint4(pk[0], pk[1], pk[2], pk[3]);
        }
    }
    if (t == 0) beff[ch] = b7[ch] + b5[ch] + b3[ch];
}

// ---------------------------------------------------------------------------
// Main: ONE BLOCK PER CHANNEL. 1024 threads = 16 waves = 4x4 (h,w) tiles of
// 16x16. The whole channel is staged once into a 161 KB f16 LDS slab
// (16 planes x 70 rows (64 + 3 zero-halo each side) x 72 cols) -> no h-halo
// staging redundancy, one barrier per channel, and 16 waves/CU (4/SIMD,
// up from 3/SIMD) since the acc register budget (64 AGPR) plus single-
// buffered bw[7] fits the 128-reg/wave cap of 4 waves/SIMD.
// Each wave computes its 16x16 (h,w) tile for ALL 16 douts -> full 64B
// coalesced output lines. Right-edge A-reads overrun into the next row's
// left-halo zeros (out-of-image -> zero is correct); the final row's
// overrun lands in the zeroed 16B pad.
// ---------------------------------------------------------------------------
__global__ __launch_bounds__(1024, 4)
void dwconv_mfma(const float* __restrict__ in,
                 const uint4* __restrict__ wfrag,
                 const float* __restrict__ beff,
                 float* __restrict__ out)
{
    __shared__ u16 slab[SLAB_U16 + 8];   // 161,296 B

    const int ch   = blockIdx.x;
    const int tid  = threadIdx.x;
    const int lane = tid & 63;

    // issue kh=0 fragment loads + bias before staging so latency hides there
    const uint4* __restrict__ wfc = wfrag + ch * FRAG_U4_PER_CH + lane;
    uint4 bw[7];
    #pragma unroll
    for (int kd = 0; kd < 7; ++kd) bw[kd] = wfc[kd * 64];
    const float bv = beff[ch];

    const float* __restrict__ inb = in + ch * CHVOL;

    // ---- stage: chunks of 4 f16 (aligned float4 global load, b64 LDS write)
    // LDS col j = iw + 8 (halo 8 left); chunk c covers iw = 4c-8, c in 0..17.
    // c<2 and halo rows (ih outside [0,64)) are all-zero.
    for (int idx = tid; idx < ND * ROWS * 18; idx += 1024) {
        const int di = idx / (ROWS * 18);
        const int rm = idx - di * (ROWS * 18);
        const int r  = rm / 18;
        const int c  = rm - r * 18;
        const int ih = r - 3;
        u32 p0 = 0u, p1 = 0u;
        if ((unsigned)ih < (unsigned)NH && c >= 2) {
            const float4 v = *(const float4*)(inb + di * PLANE + ih * NW + (c * 4 - 8));
            p0 = (u32)f16bits(v.x) | ((u32)f16bits(v.y) << 16);
            p1 = (u32)f16bits(v.z) | ((u32)f16bits(v.w) << 16);
        }
        *(uint2*)(slab + (di * ROWS + r) * RST + c * 4) = make_uint2(p0, p1);
    }
    if (tid < 8) slab[SLAB_U16 + tid] = (u16)0;   // zero the overrun pad
    __syncthreads();

    const int wv    = tid >> 6;       // 0..15 -> (h-tile, w-tile)
    const int h0    = (wv >> 2) * 16;
    const int w0    = (wv & 3) * 16;
    const int n     = lane & 15;      // B/D column (also A row m)
    const int quad  = lane >> 4;

    f32x4 acc[16];
    #pragma unroll
    for (int t = 0; t < 16; ++t) acc[t] = (f32x4){bv, bv, bv, bv};

    #pragma unroll 1
    for (int kh = 0; kh < 7; ++kh) {
        // single-buffered weight fragments (kh=0 preloaded above); L2-hot
        if (kh > 0) {
            #pragma unroll
            for (int kd = 0; kd < 7; ++kd) bw[kd] = wfc[(kh * 7 + kd) * 64];
        }

        // A row = h0 + m + kh (halo offset folded into slab layout)
        const u16* arow = slab + (h0 + n + kh) * RST + w0 + quad * 8;
        #pragma unroll
        for (int di = 0; di < ND; ++di) {
            const f16x8 Af = *(const f16x8*)(arow + di * (ROWS * RST));
            #pragma unroll
            for (int kd = 0; kd < 7; ++kd) {
                const int dout = di - kd + 3;            // folds at compile time
                if (dout < 0 || dout > 15) continue;
                acc[dout] = __builtin_amdgcn_mfma_f32_16x16x32_f16(
                                Af, __builtin_bit_cast(f16x8, bw[kd]), acc[dout], 0, 0, 0);
            }
        }
    }

    // ---- epilogue: D row = quad*4+r (h), col = n (w); out[..][h*64+w][d]
    // Full 64B per point from one wave.
    float* __restrict__ ob = out + ch * CHVOL;
    #pragma unroll
    for (int r = 0; r < 4; ++r) {
        const int h = h0 + quad * 4 + r;
        float* p = ob + (h * NW + w0 + n) * ND;
        #pragma unroll
        for (int tg = 0; tg < 4; ++tg) {
            const float4 v = make_float4(acc[4 * tg + 0][r], acc[4 * tg + 1][r],
                                         acc[4 * tg + 2][r], acc[4 * tg + 3][r]);
            *(float4*)(p + 4 * tg) = v;
        }
    }
}

extern "C" void kernel_launch(void* const* d_in, const int* in_sizes, int n_in,
                              void* d_out, int out_size, void* d_ws, size_t ws_size,
                              hipStream_t stream)
{
    const float* x  = (const float*)d_in[0];
    const float* w7 = (const float*)d_in[1];
    const float* b7 = (const float*)d_in[2];
    const float* w5 = (const float*)d_in[3];
    const float* b5 = (const float*)d_in[4];
    const float* w3 = (const float*)d_in[5];
    const float* b3 = (const float*)d_in[6];
    float* outp = (float*)d_out;

    uint4* wfrag = (uint4*)d_ws;                                  // 25,690,112 B
    float* beff  = (float*)((char*)d_ws
                            + (size_t)NCH * FRAG_U4_PER_CH * sizeof(uint4));

    build_weights<<<NCH, 64, 0, stream>>>(w7, b7, w5, b5, w3, b3, wfrag, beff);
    dwconv_mfma<<<NCH, 1024, 0, stream>>>(x, wfrag, beff, outp);
}